// Round 12
// baseline (109.456 us; speedup 1.0000x reference)
//
#include <hip/hip_runtime.h>
#include <math.h>

// ---------------------------------------------------------------------------
// KAN-Conv CIFAR net on gfx950, round 17: ONE kernel for the whole net.
// r16 (L2L3lin fusion) = 104.8us. Launch-boundary cost is calibrated at
// 6-9us each (r11: -1 launch = -9; r16: -2 launches+roundtrips = -18).
// This round removes the last boundary + h1 global roundtrip:
//  - per-image block (grid 256 x 512thr), phases: L1(v=0) -> L1(v=1) ->
//    act2 -> L2 -> act3 -> L3 -> linear, all through one 64000B LDS arena.
//  - L1 = two sequential v-half passes of the r15-verified body; pooled h1
//    stored as bf16 in 4KB LDS (feeds act_record which rounds to bf16 anyway).
//  - w3 fused IN-BLOCK in two 36.9KB chunks (o-halves); waves register-load
//    their bfr3 slice between chunk stages (4608 fuse_w/block ~ 270 cyc).
//    Kills the w3g global table and the kernel-A prep coupling.
//  - ILP: L2 K-chain split 18 -> 2x9, L3 36 -> 2x18 (dep-chain halved; we
//    run 2 waves/SIMD so MFMA latency was exposed).
// Arena (offsets in bytes, all handoffs sync'd):
//   h1 bf16[2048]   @0     (persists L1 -> act2 staging)
//   act1 u4[1836]   @4096  | w1 u4[448] @33472   (L1 phases)
//   act2 u4[2592]   @4096  | w2 u4[1152] @45568  (ends 64000)
//   h2 f32[1024]    @0     (h1 dead)
//   w3chunk u4[2304]@4096  (twice; then dead)
//   act3 u4[1600]   @4096
//   h3 f32[512]     @0     (h2 dead after act3 staged)
// ---------------------------------------------------------------------------

#define BATCH 256

typedef short bf16x8 __attribute__((ext_vector_type(8)));
typedef float f32x4  __attribute__((ext_vector_type(4)));

__device__ __forceinline__ unsigned f2bf(float f) {
    unsigned u = __float_as_uint(f);
    u += 0x7fffu + ((u >> 16) & 1u);       // round-to-nearest-even
    return u >> 16;
}
__device__ __forceinline__ float bf2f(unsigned short u) {
    return __uint_as_float(((unsigned)u) << 16);
}
__device__ __forceinline__ unsigned pk2(float a, float b) {
    return f2bf(a) | (f2bf(b) << 16);
}

__device__ __forceinline__ void bspline_basis(float x, float bs[6]) {
    const float h = 2.0f / 3.0f;
    float g[10];
#pragma unroll
    for (int i = 0; i < 10; ++i) g[i] = (float)(i - 3) * h - 1.0f;
    float b[9];
#pragma unroll
    for (int i = 0; i < 9; ++i) b[i] = (x >= g[i] && x < g[i + 1]) ? 1.0f : 0.0f;
#pragma unroll
    for (int j = 1; j <= 3; ++j) {
        const float inv_d = 1.0f / ((float)j * h);
#pragma unroll
        for (int i = 0; i + j < 9; ++i) {
            float left  = (x - g[i]) * inv_d;
            float right = (g[i + j + 1] - x) * inv_d;
            b[i] = left * b[i] + right * b[i + 1];
        }
    }
#pragma unroll
    for (int i = 0; i < 6; ++i) bs[i] = b[i];
}

// [silu, b0..b5, 0] as 8 bf16 in one uint4.
__device__ __forceinline__ uint4 act_record(float val) {
    float silu = val / (1.0f + __expf(-val));
    float bs[6];
    bspline_basis(val, bs);
    uint4 r;
    r.x = pk2(silu, bs[0]);
    r.y = pk2(bs[1], bs[2]);
    r.z = pk2(bs[3], bs[4]);
    r.w = f2bf(bs[5]);
    return r;
}

__device__ __forceinline__ uint4 fuse_w(const float* bw, const float* sw,
                                        const float* sc, int j) {
    float s = sc[j];
    uint4 r;
    r.x = pk2(bw[j],             sw[j * 6 + 0] * s);
    r.y = pk2(sw[j * 6 + 1] * s, sw[j * 6 + 2] * s);
    r.z = pk2(sw[j * 6 + 3] * s, sw[j * 6 + 4] * s);
    r.w = f2bf(sw[j * 6 + 5] * s);
    return r;
}

__global__ __launch_bounds__(512, 2) void kan_all(
        const float* __restrict__ x,
        const float* __restrict__ bw1, const float* __restrict__ sw1, const float* __restrict__ sc1,
        const float* __restrict__ bw2, const float* __restrict__ sw2, const float* __restrict__ sc2,
        const float* __restrict__ bw3, const float* __restrict__ sw3, const float* __restrict__ sc3,
        const float* __restrict__ lin_w, const float* __restrict__ lin_b,
        float* __restrict__ out) {
    constexpr int NT = 512;
    __shared__ alignas(16) unsigned char s_mem[64000];
    unsigned short* s_h1 = (unsigned short*)s_mem;        // [2048] bf16
    uint4* s_act1 = (uint4*)(s_mem + 4096);               // [1836]
    uint4* s_w1   = (uint4*)(s_mem + 33472);              // [448]
    uint4* s_act2 = (uint4*)(s_mem + 4096);               // [2592]
    uint4* s_w2   = (uint4*)(s_mem + 45568);              // [1152]
    float* s_h2   = (float*)s_mem;                        // [1024]
    uint4* s_w3c  = (uint4*)(s_mem + 4096);               // [2304]
    uint4* s_act3 = (uint4*)(s_mem + 4096);               // [1600]
    float* s_h3   = (float*)s_mem;                        // [512]

    const int tid  = threadIdx.x;
    const int n    = blockIdx.x;
    const int lane = tid & 63;
    const int wv   = tid >> 6;
    const int kg   = lane >> 4;
    const int oc   = lane & 15;
    const int m    = lane & 15;

    // ---- stage w1 [fp 28][16] (zeros for pad tap / o>=8)
    for (int i = tid; i < 448; i += NT) {
        int fp = i >> 4, o = i & 15;
        uint4 r = make_uint4(0u, 0u, 0u, 0u);
        if (fp < 27 && o < 8) r = fuse_w(bw1, sw1, sc1, o * 27 + fp);
        s_w1[i] = r;
    }

    // ================= L1: two v-half passes (r15 body) =================
    const float* xb = x + (size_t)n * 3 * 32 * 32;
#pragma unroll 1
    for (int v = 0; v < 2; ++v) {
        __syncthreads();                   // w1 staged / prev pass act reads done
        const int r0 = 16 * v - 1;
        for (int i = tid; i < 1836; i += NT) {          // 3ch x 18 x 34
            int cc  = i / 612;
            int rr  = (i / 34) % 18;
            int col = i % 34;
            int gr = r0 + rr, gc = col - 1;
            float val = 0.0f;
            if ((unsigned)gr < 32u && (unsigned)gc < 32u)
                val = xb[(cc * 32 + gr) * 32 + gc];
            s_act1[i] = act_record(val);
        }
        __syncthreads();

        bf16x8 bfr[7];
#pragma unroll
        for (int s = 0; s < 7; ++s)
            bfr[s] = *reinterpret_cast<const bf16x8*>(&s_w1[(4 * s + kg) * 16 + oc]);
        int pixoff[4];
#pragma unroll
        for (int t = 0; t < 4; ++t)
            pixoff[t] = (2 * wv + (t >> 1)) * 34 + 16 * (t & 1) + m;
        f32x4 acc[4];
#pragma unroll
        for (int t = 0; t < 4; ++t) acc[t] = (f32x4){0.f, 0.f, 0.f, 0.f};
#pragma unroll
        for (int s = 0; s < 7; ++s) {
            int tp = 4 * s + kg;
            tp = (tp > 26) ? 26 : tp;      // pad tap: B=0 anyway
            int c  = tp / 9;
            int t9 = tp - 9 * c;
            int ky = t9 / 3;
            int kx = t9 - 3 * ky;
            int base = (c * 18 + ky) * 34 + kx;
#pragma unroll
            for (int t = 0; t < 4; ++t) {
                bf16x8 a = *reinterpret_cast<const bf16x8*>(&s_act1[base + pixoff[t]]);
                acc[t] = __builtin_amdgcn_mfma_f32_16x16x32_bf16(a, bfr[s], acc[t], 0, 0, 0);
            }
        }
        // pooled h1 -> LDS bf16 (h1 region disjoint from act1: no sync needed)
        if (oc < 8) {
            f32x4 e0, e1;
#pragma unroll
            for (int p = 0; p < 4; ++p) {
                e0[p] = fmaxf(acc[0][p], acc[2][p]);
                e1[p] = fmaxf(acc[1][p], acc[3][p]);
            }
            unsigned short* hp = s_h1 + ((oc * 16) + (8 * v + wv)) * 16;
            hp[2 * kg]         = (unsigned short)f2bf(fmaxf(e0[0], e0[1]));
            hp[2 * kg + 1]     = (unsigned short)f2bf(fmaxf(e0[2], e0[3]));
            hp[8 + 2 * kg]     = (unsigned short)f2bf(fmaxf(e1[0], e1[1]));
            hp[8 + 2 * kg + 1] = (unsigned short)f2bf(fmaxf(e1[2], e1[3]));
        }
    }
    __syncthreads();                       // L1 done; h1 visible

    // ================= stage act2 (reads h1) + w2 =================
    for (int i = tid; i < 1152; i += NT) {
        int fp = i >> 4, o = i & 15;
        s_w2[i] = fuse_w(bw2, sw2, sc2, o * 72 + fp);
    }
    for (int i = tid; i < 2592; i += NT) {              // 8ch x 18 x 18
        int cc  = i / 324;
        int rr  = (i / 18) % 18;
        int col = i % 18;
        int gr = rr - 1, gc = col - 1;
        float val = 0.0f;
        if ((unsigned)gr < 16u && (unsigned)gc < 16u)
            val = bf2f(s_h1[(cc * 16 + gr) * 16 + gc]);
        s_act2[i] = act_record(val);
    }
    __syncthreads();

    // ================= L2 MFMA (K split 9+9 for ILP) =================
    {
        bf16x8 bfr2[18];
#pragma unroll
        for (int s = 0; s < 18; ++s)
            bfr2[s] = *reinterpret_cast<const bf16x8*>(&s_w2[(4 * s + kg) * 16 + oc]);
        const int p0 = (2 * wv) * 18 + m;
        const int p1 = p0 + 18;
        f32x4 a0 = (f32x4){0.f, 0.f, 0.f, 0.f}, a1 = a0, b0 = a0, b1 = a0;
#pragma unroll
        for (int s = 0; s < 18; ++s) {
            int tp = 4 * s + kg;
            int c  = tp / 9;
            int t9 = tp - 9 * c;
            int ky = t9 / 3;
            int kx = t9 - 3 * ky;
            int base = (c * 18 + ky) * 18 + kx;
            bf16x8 av0 = *reinterpret_cast<const bf16x8*>(&s_act2[base + p0]);
            bf16x8 av1 = *reinterpret_cast<const bf16x8*>(&s_act2[base + p1]);
            if (s < 9) {
                a0 = __builtin_amdgcn_mfma_f32_16x16x32_bf16(av0, bfr2[s], a0, 0, 0, 0);
                a1 = __builtin_amdgcn_mfma_f32_16x16x32_bf16(av1, bfr2[s], a1, 0, 0, 0);
            } else {
                b0 = __builtin_amdgcn_mfma_f32_16x16x32_bf16(av0, bfr2[s], b0, 0, 0, 0);
                b1 = __builtin_amdgcn_mfma_f32_16x16x32_bf16(av1, bfr2[s], b1, 0, 0, 0);
            }
        }
        a0 = a0 + b0;
        a1 = a1 + b1;
        float e0 = fmaxf(a0[0], a1[0]);
        float e1 = fmaxf(a0[1], a1[1]);
        float e2 = fmaxf(a0[2], a1[2]);
        float e3 = fmaxf(a0[3], a1[3]);
        // h2 (0..4095, h1 region, dead) disjoint from act2/w2: safe pre-sync
        s_h2[(oc * 8 + wv) * 8 + 2 * kg]     = fmaxf(e0, e1);
        s_h2[(oc * 8 + wv) * 8 + 2 * kg + 1] = fmaxf(e2, e3);
    }
    __syncthreads();                       // L2 act2 reads done; h2 visible

    // ================= w3 fused in two LDS chunks -> bfr3 regs =============
    bf16x8 bfr3[36];
    for (int i = tid; i < 2304; i += NT) { // chunk0: o 0..15
        int fp = i >> 4, o = i & 15;
        s_w3c[i] = fuse_w(bw3, sw3, sc3, o * 144 + fp);
    }
    __syncthreads();
    if (wv < 4) {
#pragma unroll
        for (int s = 0; s < 36; ++s)
            bfr3[s] = *reinterpret_cast<const bf16x8*>(&s_w3c[(4 * s + kg) * 16 + oc]);
    }
    __syncthreads();
    for (int i = tid; i < 2304; i += NT) { // chunk1: o 16..31
        int fp = i >> 4, o = 16 + (i & 15);
        s_w3c[i] = fuse_w(bw3, sw3, sc3, o * 144 + fp);
    }
    __syncthreads();
    if (wv >= 4) {
#pragma unroll
        for (int s = 0; s < 36; ++s)
            bfr3[s] = *reinterpret_cast<const bf16x8*>(&s_w3c[(4 * s + kg) * 16 + oc]);
    }
    __syncthreads();

    // ================= stage act3 (reads h2) =================
    for (int i = tid; i < 1600; i += NT) {              // 16ch x 10 x 10
        int cc  = i / 100;
        int rr  = (i / 10) % 10;
        int col = i % 10;
        int gr = rr - 1, gc = col - 1;
        float val = 0.0f;
        if ((unsigned)gr < 8u && (unsigned)gc < 8u)
            val = s_h2[(cc * 8 + gr) * 8 + gc];
        s_act3[i] = act_record(val);
    }
    __syncthreads();

    // ================= L3 MFMA (K split 18+18) =================
    {
        const int mt  = wv & 3;
        const int o03 = 16 * (wv >> 2);
        const int poff = (2 * mt + (m >> 3)) * 10 + (m & 7);
        f32x4 a3 = (f32x4){0.f, 0.f, 0.f, 0.f}, a3b = a3;
#pragma unroll
        for (int s = 0; s < 36; ++s) {
            int tp = 4 * s + kg;
            int c  = tp / 9;
            int t9 = tp - 9 * c;
            int ky = t9 / 3;
            int kx = t9 - 3 * ky;
            int base = (c * 10 + ky) * 10 + kx;
            bf16x8 av = *reinterpret_cast<const bf16x8*>(&s_act3[base + poff]);
            if (s < 18)
                a3 = __builtin_amdgcn_mfma_f32_16x16x32_bf16(av, bfr3[s], a3, 0, 0, 0);
            else
                a3b = __builtin_amdgcn_mfma_f32_16x16x32_bf16(av, bfr3[s], a3b, 0, 0, 0);
        }
        a3 = a3 + a3b;
        float q0 = fmaxf(a3[0], a3[1]);
        float q1 = fmaxf(a3[2], a3[3]);
        float y0 = fmaxf(q0, __shfl_xor(q0, 32));
        float y1 = fmaxf(q1, __shfl_xor(q1, 32));
        // h3 (0..2047, h2 region, dead) disjoint from act3: safe pre-sync
        if (kg < 2) {
            s_h3[(o03 + oc) * 16 + mt * 4 + 2 * kg]     = y0;
            s_h3[(o03 + oc) * 16 + mt * 4 + 2 * kg + 1] = y1;
        }
    }
    __syncthreads();

    // ================= linear (r16-verbatim) =================
    {
        const float4* hf = (const float4*)s_h3;
        const float4 h0v = hf[lane];
        const float4 h1v = hf[lane + 64];
#pragma unroll 1
        for (int o = wv; o < 100; o += 8) {
            const float4* wr = (const float4*)(lin_w + (size_t)o * 512);
            float4 w0 = wr[lane];
            float4 w1 = wr[lane + 64];
            float p = w0.x * h0v.x + w0.y * h0v.y + w0.z * h0v.z + w0.w * h0v.w
                    + w1.x * h1v.x + w1.y * h1v.y + w1.z * h1v.z + w1.w * h1v.w;
            p += __shfl_xor(p, 32);
            p += __shfl_xor(p, 16);
            p += __shfl_xor(p, 8);
            p += __shfl_xor(p, 4);
            p += __shfl_xor(p, 2);
            p += __shfl_xor(p, 1);
            if (lane == 0) out[(size_t)n * 100 + o] = p + lin_b[o];
        }
    }
}

extern "C" void kernel_launch(void* const* d_in, const int* in_sizes, int n_in,
                              void* d_out, int out_size, void* d_ws, size_t ws_size,
                              hipStream_t stream) {
    const float* x     = (const float*)d_in[0];
    const float* c1_bw = (const float*)d_in[1];
    const float* c1_sw = (const float*)d_in[2];
    const float* c1_sc = (const float*)d_in[3];
    const float* c2_bw = (const float*)d_in[4];
    const float* c2_sw = (const float*)d_in[5];
    const float* c2_sc = (const float*)d_in[6];
    const float* c3_bw = (const float*)d_in[7];
    const float* c3_sw = (const float*)d_in[8];
    const float* c3_sc = (const float*)d_in[9];
    const float* lin_w = (const float*)d_in[10];
    const float* lin_b = (const float*)d_in[11];
    float* out = (float*)d_out;

    // One kernel, one block per image: L1 -> L2 -> L3 -> linear in LDS.
    kan_all<<<256, 512, 0, stream>>>(
        x,
        c1_bw, c1_sw, c1_sc,
        c2_bw, c2_sw, c2_sc,
        c3_bw, c3_sw, c3_sc,
        lin_w, lin_b, out);
}

// Round 13
// 105.707 us; speedup vs baseline: 1.0355x; 1.0355x over previous
//
#include <hip/hip_runtime.h>
#include <math.h>

// ---------------------------------------------------------------------------
// KAN-Conv CIFAR net on gfx950, round 18.
// Ledger (r17 calibration): dur = kernels + ~40us workspace-poison fill
// (harness) + ~28us launch overhead. r16 kernels+gap = 36.7us GPU time beats
// r17's single 41.4us kernel (full fusion lost L1's 2-blk/CU parallelism and
// duplicated w3 fusion 256x). This round: r16 structure VERBATIM (104.8us)
// + three chain-shortening edits inside the proven bodies:
//  (1) L2 K-chain 18 -> 9+9 (2 accumulators): dependent-MFMA latency at
//      2 waves/SIMD halved.
//  (2) L3 K-chain 36 -> 18+18 (same).
//  (3) linear: 2-deep software pipeline -- next o's two float4 w-loads
//      issue before the current 6-shfl reduce chain (overlaps ~300cyc L2
//      latency x 13 iters/wave).
// ---------------------------------------------------------------------------

#define BATCH 256

typedef short bf16x8 __attribute__((ext_vector_type(8)));
typedef float f32x4  __attribute__((ext_vector_type(4)));

__device__ __forceinline__ unsigned f2bf(float f) {
    unsigned u = __float_as_uint(f);
    u += 0x7fffu + ((u >> 16) & 1u);       // round-to-nearest-even
    return u >> 16;
}
__device__ __forceinline__ unsigned pk2(float a, float b) {
    return f2bf(a) | (f2bf(b) << 16);
}

__device__ __forceinline__ void bspline_basis(float x, float bs[6]) {
    const float h = 2.0f / 3.0f;
    float g[10];
#pragma unroll
    for (int i = 0; i < 10; ++i) g[i] = (float)(i - 3) * h - 1.0f;
    float b[9];
#pragma unroll
    for (int i = 0; i < 9; ++i) b[i] = (x >= g[i] && x < g[i + 1]) ? 1.0f : 0.0f;
#pragma unroll
    for (int j = 1; j <= 3; ++j) {
        const float inv_d = 1.0f / ((float)j * h);
#pragma unroll
        for (int i = 0; i + j < 9; ++i) {
            float left  = (x - g[i]) * inv_d;
            float right = (g[i + j + 1] - x) * inv_d;
            b[i] = left * b[i] + right * b[i + 1];
        }
    }
#pragma unroll
    for (int i = 0; i < 6; ++i) bs[i] = b[i];
}

// [silu, b0..b5, 0] as 8 bf16 in one uint4.
__device__ __forceinline__ uint4 act_record(float val) {
    float silu = val / (1.0f + __expf(-val));
    float bs[6];
    bspline_basis(val, bs);
    uint4 r;
    r.x = pk2(silu, bs[0]);
    r.y = pk2(bs[1], bs[2]);
    r.z = pk2(bs[3], bs[4]);
    r.w = f2bf(bs[5]);
    return r;
}

__device__ __forceinline__ uint4 fuse_w(const float* bw, const float* sw,
                                        const float* sc, int j) {
    float s = sc[j];
    uint4 r;
    r.x = pk2(bw[j],             sw[j * 6 + 0] * s);
    r.y = pk2(sw[j * 6 + 1] * s, sw[j * 6 + 2] * s);
    r.z = pk2(sw[j * 6 + 3] * s, sw[j * 6 + 4] * s);
    r.w = f2bf(sw[j * 6 + 5] * s);
    return r;
}

// ---------------------------------------------------------------------------
// Kernel A: L1 conv+pool (r15-verbatim) + prep of L3 bf16 weight table w3g.
// grid 512 (img x vhalf) x 512 threads, 2 blocks/CU.
// ---------------------------------------------------------------------------
__global__ __launch_bounds__(512, 4) void kan_l1(
        const float* __restrict__ x,
        const float* __restrict__ bw, const float* __restrict__ sw,
        const float* __restrict__ sc,
        const float* __restrict__ bw3, const float* __restrict__ sw3,
        const float* __restrict__ sc3,
        uint4* __restrict__ w3g,
        float* __restrict__ out) {
    constexpr int C = 3, H = 32, W = 32, F = 27, FP = 28, NS = 7;
    constexpr int RT = 18, TC = 34, NT = 512;

    __shared__ uint4 s_act[C * RT * TC];           // 1836 recs = 29.4KB
    __shared__ uint4 s_w[FP * 16];                 // 7.2KB

    const int tid = threadIdx.x;
    const int bid = blockIdx.x;
    const int b   = bid >> 1;
    const int v   = bid & 1;

    // ---- prep w3g (blocks 0..8): [tap][32] bf16x8
    if (bid < 9) {
        int i = bid * NT + tid;
        if (i < 4608) {
            int o = i / 144, fp = i % 144;
            w3g[fp * 32 + o] = fuse_w(bw3, sw3, sc3, i);
        }
    }

    // ---- stage own weights [fp][16] (zeros for pad tap / o>=8)
    for (int i = tid; i < FP * 16; i += NT) {
        int fp = i >> 4, o = i & 15;
        uint4 r = make_uint4(0u, 0u, 0u, 0u);
        if (fp < F && o < 8) r = fuse_w(bw, sw, sc, o * F + fp);
        s_w[i] = r;
    }

    // ---- stage act records
    const int r0 = 16 * v - 1;
    const float* xb = x + (size_t)b * C * H * W;
    for (int i = tid; i < C * RT * TC; i += NT) {
        int cc  = i / (RT * TC);
        int rr  = (i / TC) % RT;
        int col = i % TC;
        int gr = r0 + rr, gc = col - 1;
        float val = 0.0f;
        if ((unsigned)gr < (unsigned)H && (unsigned)gc < (unsigned)W)
            val = xb[(cc * H + gr) * W + gc];
        s_act[i] = act_record(val);
    }
    __syncthreads();

    const int lane = tid & 63;
    const int wv   = tid >> 6;
    const int kg   = lane >> 4;
    const int oc   = lane & 15;
    const int m    = lane & 15;

    bf16x8 bfr[NS];
#pragma unroll
    for (int s = 0; s < NS; ++s)
        bfr[s] = *reinterpret_cast<const bf16x8*>(&s_w[(4 * s + kg) * 16 + oc]);

    int pixoff[4];
#pragma unroll
    for (int t = 0; t < 4; ++t)
        pixoff[t] = (2 * wv + (t >> 1)) * TC + 16 * (t & 1) + m;

    f32x4 acc[4];
#pragma unroll
    for (int t = 0; t < 4; ++t) acc[t] = (f32x4){0.f, 0.f, 0.f, 0.f};

#pragma unroll
    for (int s = 0; s < NS; ++s) {
        int tp = 4 * s + kg;
        tp = (tp > F - 1) ? F - 1 : tp;            // pad tap: B=0 anyway
        int c  = tp / 9;
        int t9 = tp - 9 * c;
        int ky = t9 / 3;
        int kx = t9 - 3 * ky;
        int base = (c * RT + ky) * TC + kx;
#pragma unroll
        for (int t = 0; t < 4; ++t) {
            bf16x8 a = *reinterpret_cast<const bf16x8*>(&s_act[base + pixoff[t]]);
            acc[t] = __builtin_amdgcn_mfma_f32_16x16x32_bf16(a, bfr[s], acc[t], 0, 0, 0);
        }
    }

    if (oc < 8) {
        f32x4 e0, e1;
#pragma unroll
        for (int p = 0; p < 4; ++p) {
            e0[p] = fmaxf(acc[0][p], acc[2][p]);
            e1[p] = fmaxf(acc[1][p], acc[3][p]);
        }
        float* op = out + (((size_t)b * 8 + oc) * 16 + (8 * v + wv)) * 16;
        op[2 * kg]         = fmaxf(e0[0], e0[1]);
        op[2 * kg + 1]     = fmaxf(e0[2], e0[3]);
        op[8 + 2 * kg]     = fmaxf(e1[0], e1[1]);
        op[8 + 2 * kg + 1] = fmaxf(e1[2], e1[3]);
    }
}

// ---------------------------------------------------------------------------
// Kernel B: L2 conv+pool -> L3 conv+pool -> linear, one block per image.
// grid 256 x 512 threads.  LDS arena phases:
//   P1: act2[2592]u4 (0..41471) | w2[1152]u4 (41472..59903)
//   P2: h2[1024]f   (0..4095)   | act3[1600]u4 (4096..29695)
//   P3: h3[512]f    (0..2047)
// ---------------------------------------------------------------------------
__global__ __launch_bounds__(512, 2) void kan_l2l3lin(
        const float* __restrict__ h1,
        const float* __restrict__ bw2, const float* __restrict__ sw2,
        const float* __restrict__ sc2,
        const uint4* __restrict__ w3g,
        const float* __restrict__ lin_w, const float* __restrict__ lin_b,
        float* __restrict__ out) {
    constexpr int NT = 512;
    __shared__ alignas(16) unsigned char s_mem[59904];
    uint4* s_act2 = (uint4*)s_mem;                 // [2592]
    uint4* s_w2   = (uint4*)(s_mem + 41472);       // [1152]
    float* s_h2   = (float*)s_mem;                 // [1024]
    uint4* s_act3 = (uint4*)(s_mem + 4096);        // [1600]
    float* s_h3   = (float*)s_mem;                 // [512]

    const int tid = threadIdx.x;
    const int n   = blockIdx.x;
    const int lane = tid & 63;
    const int wv   = tid >> 6;
    const int kg   = lane >> 4;
    const int oc   = lane & 15;
    const int m    = lane & 15;

    // ---- P1 stage: w2 fused [fp][16]
    for (int i = tid; i < 72 * 16; i += NT) {
        int fp = i >> 4, o = i & 15;
        s_w2[i] = fuse_w(bw2, sw2, sc2, o * 72 + fp);
    }
    // ---- P1 stage: act2 from h1 (8ch x 18 x 18, halo)
    const float* xb = h1 + (size_t)n * 8 * 16 * 16;
    for (int i = tid; i < 8 * 18 * 18; i += NT) {
        int cc  = i / 324;
        int rr  = (i / 18) % 18;
        int col = i % 18;
        int gr = rr - 1, gc = col - 1;
        float val = 0.0f;
        if ((unsigned)gr < 16u && (unsigned)gc < 16u)
            val = xb[(cc * 16 + gr) * 16 + gc];
        s_act2[i] = act_record(val);
    }
    __syncthreads();

    // ---- L2 MFMA (K split 9+9 for ILP): 2 row-tiles per wave
    {
        bf16x8 bfr2[18];
#pragma unroll
        for (int s = 0; s < 18; ++s)
            bfr2[s] = *reinterpret_cast<const bf16x8*>(&s_w2[(4 * s + kg) * 16 + oc]);
        const int p0 = (2 * wv) * 18 + m;
        const int p1 = p0 + 18;
        f32x4 a0 = (f32x4){0.f, 0.f, 0.f, 0.f}, a1 = a0, b0 = a0, b1 = a0;
#pragma unroll
        for (int s = 0; s < 18; ++s) {
            int tp = 4 * s + kg;
            int c  = tp / 9;
            int t9 = tp - 9 * c;
            int ky = t9 / 3;
            int kx = t9 - 3 * ky;
            int base = (c * 18 + ky) * 18 + kx;
            bf16x8 av0 = *reinterpret_cast<const bf16x8*>(&s_act2[base + p0]);
            bf16x8 av1 = *reinterpret_cast<const bf16x8*>(&s_act2[base + p1]);
            if (s < 9) {
                a0 = __builtin_amdgcn_mfma_f32_16x16x32_bf16(av0, bfr2[s], a0, 0, 0, 0);
                a1 = __builtin_amdgcn_mfma_f32_16x16x32_bf16(av1, bfr2[s], a1, 0, 0, 0);
            } else {
                b0 = __builtin_amdgcn_mfma_f32_16x16x32_bf16(av0, bfr2[s], b0, 0, 0, 0);
                b1 = __builtin_amdgcn_mfma_f32_16x16x32_bf16(av1, bfr2[s], b1, 0, 0, 0);
            }
        }
        a0 = a0 + b0;
        a1 = a1 + b1;
        float e0 = fmaxf(a0[0], a1[0]);
        float e1 = fmaxf(a0[1], a1[1]);
        float e2 = fmaxf(a0[2], a1[2]);
        float e3 = fmaxf(a0[3], a1[3]);
        __syncthreads();                           // act2/w2 reads done
        // pooled h2: ch=oc, prow=wv, pcols 2kg,2kg+1
        s_h2[(oc * 8 + wv) * 8 + 2 * kg]     = fmaxf(e0, e1);
        s_h2[(oc * 8 + wv) * 8 + 2 * kg + 1] = fmaxf(e2, e3);
    }
    __syncthreads();

    // ---- P2 stage: act3 from LDS h2 (16ch x 10 x 10, halo)
    for (int i = tid; i < 16 * 10 * 10; i += NT) {
        int cc  = i / 100;
        int rr  = (i / 10) % 10;
        int col = i % 10;
        int gr = rr - 1, gc = col - 1;
        float val = 0.0f;
        if ((unsigned)gr < 8u && (unsigned)gc < 8u)
            val = s_h2[(cc * 8 + gr) * 8 + gc];
        s_act3[i] = act_record(val);
    }
    __syncthreads();

    // ---- L3 MFMA (K split 18+18): wave wv -> mt=wv&3, o-half 16*(wv>>2)
    {
        const int mt  = wv & 3;
        const int o03 = 16 * (wv >> 2);
        bf16x8 bfr3[36];
#pragma unroll
        for (int s = 0; s < 36; ++s)
            bfr3[s] = *reinterpret_cast<const bf16x8*>(&w3g[(4 * s + kg) * 32 + o03 + oc]);
        const int poff = (2 * mt + (m >> 3)) * 10 + (m & 7);
        f32x4 a3 = (f32x4){0.f, 0.f, 0.f, 0.f}, a3b = a3;
#pragma unroll
        for (int s = 0; s < 36; ++s) {
            int tp = 4 * s + kg;
            int c  = tp / 9;
            int t9 = tp - 9 * c;
            int ky = t9 / 3;
            int kx = t9 - 3 * ky;
            int base = (c * 10 + ky) * 10 + kx;
            bf16x8 av = *reinterpret_cast<const bf16x8*>(&s_act3[base + poff]);
            if (s < 18)
                a3 = __builtin_amdgcn_mfma_f32_16x16x32_bf16(av, bfr3[s], a3, 0, 0, 0);
            else
                a3b = __builtin_amdgcn_mfma_f32_16x16x32_bf16(av, bfr3[s], a3b, 0, 0, 0);
        }
        a3 = a3 + a3b;
        float q0 = fmaxf(a3[0], a3[1]);
        float q1 = fmaxf(a3[2], a3[3]);
        float y0 = fmaxf(q0, __shfl_xor(q0, 32));
        float y1 = fmaxf(q1, __shfl_xor(q1, 32));
        // h3 (bytes 0..2047) disjoint from act3 (4096+): no pre-sync needed
        if (kg < 2) {
            s_h3[(o03 + oc) * 16 + mt * 4 + 2 * kg]     = y0;
            s_h3[(o03 + oc) * 16 + mt * 4 + 2 * kg + 1] = y1;
        }
    }
    __syncthreads();

    // ---- linear: 2-deep pipelined w-row loads + shfl reduce
    {
        const float4* hf = (const float4*)s_h3;
        const float4 h0v = hf[lane];
        const float4 h1v = hf[lane + 64];
        const float4* wr = (const float4*)(lin_w + (size_t)wv * 512);
        float4 w0 = wr[lane];
        float4 w1 = wr[lane + 64];
#pragma unroll 1
        for (int o = wv; o < 100; o += 8) {
            float4 nw0, nw1;
            const int on = o + 8;
            if (on < 100) {
                const float4* wn = (const float4*)(lin_w + (size_t)on * 512);
                nw0 = wn[lane];
                nw1 = wn[lane + 64];
            }
            float p = w0.x * h0v.x + w0.y * h0v.y + w0.z * h0v.z + w0.w * h0v.w
                    + w1.x * h1v.x + w1.y * h1v.y + w1.z * h1v.z + w1.w * h1v.w;
            p += __shfl_xor(p, 32);
            p += __shfl_xor(p, 16);
            p += __shfl_xor(p, 8);
            p += __shfl_xor(p, 4);
            p += __shfl_xor(p, 2);
            p += __shfl_xor(p, 1);
            if (lane == 0) out[(size_t)n * 100 + o] = p + lin_b[o];
            w0 = nw0;
            w1 = nw1;
        }
    }
}

extern "C" void kernel_launch(void* const* d_in, const int* in_sizes, int n_in,
                              void* d_out, int out_size, void* d_ws, size_t ws_size,
                              hipStream_t stream) {
    const float* x     = (const float*)d_in[0];
    const float* c1_bw = (const float*)d_in[1];
    const float* c1_sw = (const float*)d_in[2];
    const float* c1_sc = (const float*)d_in[3];
    const float* c2_bw = (const float*)d_in[4];
    const float* c2_sw = (const float*)d_in[5];
    const float* c2_sc = (const float*)d_in[6];
    const float* c3_bw = (const float*)d_in[7];
    const float* c3_sw = (const float*)d_in[8];
    const float* c3_sc = (const float*)d_in[9];
    const float* lin_w = (const float*)d_in[10];
    const float* lin_b = (const float*)d_in[11];
    float* out = (float*)d_out;

    float* ws = (float*)d_ws;
    float* h1 = ws;                      // 256*8*16*16 = 524288 floats
    uint4* w3g = (uint4*)(h1 + 524288);  // 4608 records = 73728 B

    // Kernel A: L1 [256,3,32,32] -> h1 [256,8,16,16]; + w3g prep (blocks 0-8).
    kan_l1<<<512, 512, 0, stream>>>(x, c1_bw, c1_sw, c1_sc,
                                    c3_bw, c3_sw, c3_sc, w3g, h1);
    // Kernel B: per-image L2 -> L3 -> linear. 256 blocks x 512.
    kan_l2l3lin<<<256, 512, 0, stream>>>(h1, c2_bw, c2_sw, c2_sc,
                                         w3g, lin_w, lin_b, out);
}